// Round 6
// baseline (68.516 us; speedup 1.0000x reference)
//
#include <hip/hip_runtime.h>

// SpikePool: [N=16,C=128,H=64,W=64,T=8] f32 -> [16,128,32,32,8] f32
//   x_out = 2x2 spatial avg-pool + mean of 2 time chunks  (t in 0..3)
//   out[...,0:4] = IF-spikes(x_out)
//   out[...,4:8] = IF-spikes(fmod(x_out,TH) + x_out)
//
// R6 structure: EIGHT threads per output pixel, one float4 load each.
// Lane addresses are contiguous within the wave -> every global load
// instruction covers fully-dense cache lines (R1's 1-thread/pixel layout
// touched each line 4x at 16B/lane/64B-stride). Pool sums built with
// width-8 shfl_down chains preserving the reference's left-association
// ((x00+x01)+x10)+x11; xo broadcast to all 8 lanes; every lane runs both
// IF scans (uniform, no divergence); lane j stores out[P*8+j] -> dense
// dword stores.
// History: nt hints = 2.8x regression (nt stores bypass L2 combining,
// 2x WRITE_SIZE); 2px/thread = +20% regression (liveness serializes).

#define TH 0.999f

typedef float f4 __attribute__((ext_vector_type(4)));

__device__ __forceinline__ f4 shfl_down4(f4 v, unsigned d) {
    f4 r;
    r.x = __shfl_down(v.x, d, 8);
    r.y = __shfl_down(v.y, d, 8);
    r.z = __shfl_down(v.z, d, 8);
    r.w = __shfl_down(v.w, d, 8);
    return r;
}

__device__ __forceinline__ f4 bcast4(f4 v) {  // broadcast from lane 0 of each 8-group
    f4 r;
    r.x = __shfl(v.x, 0, 8);
    r.y = __shfl(v.y, 0, 8);
    r.z = __shfl(v.z, 0, 8);
    r.w = __shfl(v.w, 0, 8);
    return r;
}

__global__ __launch_bounds__(256) void spikepool_kernel(
    const float* __restrict__ x, float* __restrict__ out)
{
    const int T = blockIdx.x * 256 + threadIdx.x;  // 16,777,216 threads
    const int j = T & 7;   // slot within pixel: (row=j>>2, wsel=(j>>1)&1, thalf=j&1)
    const int P = T >> 3;  // output pixel

    const int w  = P & 31;         // W/2 = 32
    const int h  = (P >> 5) & 31;  // H/2 = 32
    const int nc = P >> 10;        // n*C + c

    // float offset of f4 #j of pixel P:
    //   base(P) + row*512 + wsel*8 + thalf*4
    const size_t base = (size_t)nc * 32768 + (size_t)h * 1024 + (size_t)w * 16
                      + (size_t)(j >> 2) * 512 + (size_t)((j >> 1) & 1) * 8
                      + (size_t)(j & 1) * 4;
    const f4 v = *reinterpret_cast<const f4*>(x + base);

    // Left-associated sum chain over the 2x2 window, per time-chunk:
    //   lane0: ((v0+v2)+v4)+v6 = ((x00+x01)+x10)+x11 over t0..3 (chunk 0)
    //   lane1: ((v1+v3)+v5)+v7 =   same spatial order over t4..7 (chunk 1)
    f4 s = v + shfl_down4(v, 2);
    s = s + shfl_down4(v, 4);
    s = s + shfl_down4(v, 6);

    const f4 s1 = shfl_down4(s, 1);          // lane0 <- lane1's chunk-1 sum
    f4 xo = (s * 0.25f + s1 * 0.25f) * 0.5f; // valid on lane 0 only
    xo = bcast4(xo);                          // now valid on all 8 lanes

    // train 0: input = x_out
    f4 o03;
    {
        float vv = 0.0f;
#pragma unroll
        for (int t = 0; t < 4; ++t) {
            float u = vv + xo[t];
            float sp = (u >= TH) ? 1.0f : 0.0f;
            o03[t] = sp;
            vv = u - sp * TH;
        }
    }
    // train 1: input = fmod(x_out, TH) + x_out ; x_out in [0,1) so fmod
    // is exactly (x>=TH ? x-TH : x) (Sterbenz-exact subtraction).
    f4 o47;
    {
        float vv = 0.0f;
#pragma unroll
        for (int t = 0; t < 4; ++t) {
            float m  = (xo[t] >= TH) ? (xo[t] - TH) : xo[t];
            float u  = vv + (m + xo[t]);
            float sp = (u >= TH) ? 1.0f : 0.0f;
            o47[t] = sp;
            vv = u - sp * TH;
        }
    }

    // lane j writes out[P*8 + j]: select component j from (o03|o47)
    const f4 tr = (j & 4) ? o47 : o03;
    const float lohi = (j & 1) ? tr[1] : tr[0];
    const float hihi = (j & 1) ? tr[3] : tr[2];
    const float val  = (j & 2) ? hihi : lohi;

    out[T] = val;  // dense: lane L -> 4B at lane stride 4B
}

extern "C" void kernel_launch(void* const* d_in, const int* in_sizes, int n_in,
                              void* d_out, int out_size, void* d_ws, size_t ws_size,
                              hipStream_t stream) {
    const float* x = (const float*)d_in[0];
    float* out = (float*)d_out;
    // 2,097,152 output pixels x 8 threads = 16,777,216 threads
    spikepool_kernel<<<65536, 256, 0, stream>>>(x, out);
}